// Round 1
// baseline (210.214 us; speedup 1.0000x reference)
//
#include <hip/hip_runtime.h>
#include <stdint.h>

#define C_DIM 512
#define HW_N  1024
#define CPG   64
#define EPS_GN 1e-5f
#define SCALE_QK 0.044194173824159216f   // 512^-0.5

typedef __attribute__((ext_vector_type(8))) __bf16 bf16x8v;
typedef __attribute__((ext_vector_type(4))) float  f32x4;

typedef __attribute__((address_space(1))) void gvoid_t;
typedef __attribute__((address_space(3))) void lvoid_t;

__device__ __forceinline__ void gload_lds16(const void* g, void* l) {
  __builtin_amdgcn_global_load_lds((gvoid_t*)g, (lvoid_t*)l, 16, 0, 0);
}

__device__ __forceinline__ uint16_t f2bfbits(float f) {
  __bf16 h = (__bf16)f;
  return __builtin_bit_cast(uint16_t, h);
}

// ---------------------------------------------------------------------------
// GroupNorm: one block per (batch, group). Stats over 64ch x 1024px, then
// normalize + LDS transpose, writing hn^T as bf16 [N=1024][C=512] (K-major
// for all downstream GEMMs).
// ---------------------------------------------------------------------------
__global__ __launch_bounds__(512)
void gn_kernel(const float* __restrict__ x, const float* __restrict__ gnw,
               const float* __restrict__ gnb, __bf16* __restrict__ hn, int b0)
{
  const int g  = blockIdx.x & 7;
  const int bl = blockIdx.x >> 3;
  const long long xbase = ((long long)(b0 + bl) * C_DIM + g * CPG) * HW_N;
  const int t = threadIdx.x;

  float s1 = 0.f, s2 = 0.f;
  const float4* xv = (const float4*)(x + xbase);
  for (int i = t; i < CPG * HW_N / 4; i += 512) {
    float4 v = xv[i];
    s1 += v.x + v.y + v.z + v.w;
    s2 += v.x * v.x + v.y * v.y + v.z * v.z + v.w * v.w;
  }
  #pragma unroll
  for (int off = 32; off; off >>= 1) {
    s1 += __shfl_xor(s1, off);
    s2 += __shfl_xor(s2, off);
  }
  __shared__ float red[2][8];
  const int w = t >> 6, l = t & 63;
  if (l == 0) { red[0][w] = s1; red[1][w] = s2; }
  __syncthreads();
  s1 = 0.f; s2 = 0.f;
  #pragma unroll
  for (int i = 0; i < 8; ++i) { s1 += red[0][i]; s2 += red[1][i]; }
  const float mean = s1 * (1.f / 65536.f);
  const float var  = s2 * (1.f / 65536.f) - mean * mean;
  const float rstd = rsqrtf(var + EPS_GN);

  __shared__ float tile[64][65];   // +1 pad: conflict-free transpose
  __bf16* outb = hn + (long long)bl * HW_N * C_DIM + g * CPG;
  for (int n0 = 0; n0 < HW_N; n0 += 64) {
    __syncthreads();
    #pragma unroll
    for (int rep = 0; rep < 8; ++rep) {
      const int cl = rep * 8 + (t >> 6);
      const int nl = t & 63;
      const float xval = x[xbase + (long long)cl * HW_N + n0 + nl];
      tile[cl][nl] = (xval - mean) * rstd * gnw[g * CPG + cl] + gnb[g * CPG + cl];
    }
    __syncthreads();
    #pragma unroll
    for (int rep = 0; rep < 8; ++rep) {
      const int nl = rep * 8 + (t >> 6);
      const int cl = t & 63;
      outb[(long long)(n0 + nl) * C_DIM + cl] = (__bf16)tile[cl][nl];
    }
  }
}

// ---------------------------------------------------------------------------
// fp32 -> bf16 weight conversion
// ---------------------------------------------------------------------------
__global__ __launch_bounds__(256)
void cvt_kernel(const float* __restrict__ src, __bf16* __restrict__ dst, int n4)
{
  int i = blockIdx.x * 256 + threadIdx.x;
  if (i < n4) {
    float4 v = ((const float4*)src)[i];
    uint32_t lo = (uint32_t)f2bfbits(v.x) | ((uint32_t)f2bfbits(v.y) << 16);
    uint32_t hi = (uint32_t)f2bfbits(v.z) | ((uint32_t)f2bfbits(v.w) << 16);
    ((uint2*)dst)[i] = make_uint2(lo, hi);
  }
}

// ---------------------------------------------------------------------------
// Row softmax over S [rows][1024] fp32 -> P bf16. One block (256 thr) per row.
// ---------------------------------------------------------------------------
__global__ __launch_bounds__(256)
void softmax_kernel(const float* __restrict__ S, __bf16* __restrict__ P)
{
  const long long row = blockIdx.x;
  const float* s = S + row * HW_N;
  const int t = threadIdx.x;
  float4 v = ((const float4*)s)[t];
  float m = fmaxf(fmaxf(v.x, v.y), fmaxf(v.z, v.w));
  #pragma unroll
  for (int off = 32; off; off >>= 1) m = fmaxf(m, __shfl_xor(m, off));
  __shared__ float redm[4];
  __shared__ float reds[4];
  const int w = t >> 6, l = t & 63;
  if (l == 0) redm[w] = m;
  __syncthreads();
  m = fmaxf(fmaxf(redm[0], redm[1]), fmaxf(redm[2], redm[3]));
  float e0 = __expf(v.x - m), e1 = __expf(v.y - m);
  float e2 = __expf(v.z - m), e3 = __expf(v.w - m);
  float sum = e0 + e1 + e2 + e3;
  #pragma unroll
  for (int off = 32; off; off >>= 1) sum += __shfl_xor(sum, off);
  if (l == 0) reds[w] = sum;
  __syncthreads();
  sum = reds[0] + reds[1] + reds[2] + reds[3];
  const float inv = 1.f / sum;
  uint32_t lo = (uint32_t)f2bfbits(e0 * inv) | ((uint32_t)f2bfbits(e1 * inv) << 16);
  uint32_t hi = (uint32_t)f2bfbits(e2 * inv) | ((uint32_t)f2bfbits(e3 * inv) << 16);
  ((uint2*)(P + row * HW_N))[t] = make_uint2(lo, hi);
}

// ---------------------------------------------------------------------------
// Generic bf16 GEMM, C[M][N] = A[M][K] x B[N][K]^T  (both K-major), m97-style:
// 128x128 tile, BK=32, 4 waves (2x2), global_load_lds dwordx4 staging,
// mfma_f32_16x16x32_bf16. OUTM: 0=bf16, 1=f32+bias_row+residual, 2=f32 plain.
// BIASM: 0=none, 1=per-col, 2=per-row. DO_SCALE: multiply after bias.
// ---------------------------------------------------------------------------
template<int OUTM, int BIASM, bool DO_SCALE>
__global__ __launch_bounds__(256)
void gemm_bt(const __bf16* __restrict__ Amat, const __bf16* __restrict__ Bmat,
             void* __restrict__ Cmat,
             const float* __restrict__ bias,
             const float* __restrict__ resid,
             int lda, int ldb, int ldc,
             long long aStride, long long bStride, long long cStride,
             float scale, int K)
{
  __shared__ alignas(16) __bf16 As[128 * 32];
  __shared__ alignas(16) __bf16 Bs[128 * 32];

  const int t  = threadIdx.x;
  const int w  = t >> 6;
  const int l  = t & 63;
  const int b  = blockIdx.z;
  const int n0 = blockIdx.x * 128;
  const int m0 = blockIdx.y * 128;

  const __bf16* Ab = Amat + (long long)b * aStride;
  const __bf16* Bb = Bmat + (long long)b * bStride;

  const int lr = l & 15;
  const int lg = l >> 4;
  const int wm = w >> 1;
  const int wn = w & 1;

  f32x4 acc[4][4];
  #pragma unroll
  for (int i = 0; i < 4; ++i)
    #pragma unroll
    for (int j = 0; j < 4; ++j)
      acc[i][j] = (f32x4){0.f, 0.f, 0.f, 0.f};

  // staging geometry: tile is 128 rows x 32 bf16 (64B/row); wave w covers
  // flat bytes [c*4096 + w*1024, +1024) , lane l -> +l*16 (linear LDS dest)
  const int flat0 = w * 1024 + l * 16;
  const int rowA  = flat0 >> 6;
  const int colA  = (flat0 & 63) >> 1;

  for (int k0 = 0; k0 < K; k0 += 32) {
    gload_lds16(Ab + (long long)(m0 + rowA     ) * lda + (k0 + colA), (char*)As + (w * 1024));
    gload_lds16(Ab + (long long)(m0 + rowA + 64) * lda + (k0 + colA), (char*)As + (4096 + w * 1024));
    gload_lds16(Bb + (long long)(n0 + rowA     ) * ldb + (k0 + colA), (char*)Bs + (w * 1024));
    gload_lds16(Bb + (long long)(n0 + rowA + 64) * ldb + (k0 + colA), (char*)Bs + (4096 + w * 1024));
    __syncthreads();

    bf16x8v af[4], bf[4];
    #pragma unroll
    for (int mi = 0; mi < 4; ++mi)
      af[mi] = *(const bf16x8v*)&As[(wm * 64 + mi * 16 + lr) * 32 + lg * 8];
    #pragma unroll
    for (int ni = 0; ni < 4; ++ni)
      bf[ni] = *(const bf16x8v*)&Bs[(wn * 64 + ni * 16 + lr) * 32 + lg * 8];

    #pragma unroll
    for (int mi = 0; mi < 4; ++mi)
      #pragma unroll
      for (int ni = 0; ni < 4; ++ni)
        acc[mi][ni] = __builtin_amdgcn_mfma_f32_16x16x32_bf16(af[mi], bf[ni], acc[mi][ni], 0, 0, 0);
    __syncthreads();
  }

  // epilogue: C/D layout col=lane&15, row=(lane>>4)*4+reg  [m89-verified]
  const int orow = m0 + wm * 64 + lg * 4;
  const int ocol = n0 + wn * 64 + lr;

  if (OUTM == 0) {
    __bf16* Cb = (__bf16*)Cmat + (long long)b * cStride;
    #pragma unroll
    for (int mi = 0; mi < 4; ++mi) {
      #pragma unroll
      for (int ni = 0; ni < 4; ++ni) {
        const int cc = ocol + ni * 16;
        const float cbias = (BIASM == 1) ? bias[cc] : 0.f;
        #pragma unroll
        for (int r = 0; r < 4; ++r) {
          const int rr = orow + mi * 16 + r;
          float v = acc[mi][ni][r];
          if (BIASM == 1) v += cbias;
          if (BIASM == 2) v += bias[rr];
          if (DO_SCALE) v *= scale;
          Cb[(long long)rr * ldc + cc] = (__bf16)v;
        }
      }
    }
  } else {
    float* Cf = (float*)Cmat + (long long)b * cStride;
    const float* Rf = resid + (long long)b * cStride;  // only deref'd if OUTM==1
    #pragma unroll
    for (int mi = 0; mi < 4; ++mi) {
      #pragma unroll
      for (int ni = 0; ni < 4; ++ni) {
        const int cc = ocol + ni * 16;
        const float cbias = (BIASM == 1) ? bias[cc] : 0.f;
        #pragma unroll
        for (int r = 0; r < 4; ++r) {
          const int rr = orow + mi * 16 + r;
          float v = acc[mi][ni][r];
          if (BIASM == 1) v += cbias;
          if (BIASM == 2) v += bias[rr];
          if (DO_SCALE) v *= scale;
          const long long idx = (long long)rr * ldc + cc;
          if (OUTM == 1) v += Rf[idx];
          Cf[idx] = v;
        }
      }
    }
  }
}

// ---------------------------------------------------------------------------
extern "C" void kernel_launch(void* const* d_in, const int* in_sizes, int n_in,
                              void* d_out, int out_size, void* d_ws, size_t ws_size,
                              hipStream_t stream)
{
  const float* x   = (const float*)d_in[0];
  const float* gnw = (const float*)d_in[1];
  const float* gnb = (const float*)d_in[2];
  const float* wq  = (const float*)d_in[3];
  const float* bq  = (const float*)d_in[4];
  const float* wk  = (const float*)d_in[5];
  const float* bk  = (const float*)d_in[6];
  const float* wv  = (const float*)d_in[7];
  const float* bv  = (const float*)d_in[8];
  const float* wo  = (const float*)d_in[9];
  const float* bo  = (const float*)d_in[10];
  (void)in_sizes; (void)n_in; (void)out_size;

  const int Btot = 16;
  size_t used = 0;
  char* base = (char*)d_ws;
  auto carve = [&](size_t bytes) -> void* {
    used = (used + 255) & ~(size_t)255;
    void* p = base + used;
    used += bytes;
    return p;
  };

  __bf16* wqb = (__bf16*)carve((size_t)C_DIM * C_DIM * 2);
  __bf16* wkb = (__bf16*)carve((size_t)C_DIM * C_DIM * 2);
  __bf16* wvb = (__bf16*)carve((size_t)C_DIM * C_DIM * 2);
  __bf16* wob = (__bf16*)carve((size_t)C_DIM * C_DIM * 2);

  // per-batch scratch: hn,q,k,vt,o1 (1MB ea) + S fp32 (4MB) + P bf16 (2MB)
  const size_t perB = (size_t)HW_N * C_DIM * 2 * 5
                    + (size_t)HW_N * HW_N * 4
                    + (size_t)HW_N * HW_N * 2
                    + 8 * 256;
  size_t rem = (ws_size > used + 4096) ? (ws_size - used - 4096) : 0;
  int NB = (int)(rem / perB);
  if (NB < 1) NB = 1;
  if (NB > Btot) NB = Btot;

  __bf16* hn  = (__bf16*)carve((size_t)NB * HW_N * C_DIM * 2);
  __bf16* qb  = (__bf16*)carve((size_t)NB * HW_N * C_DIM * 2);
  __bf16* kb  = (__bf16*)carve((size_t)NB * HW_N * C_DIM * 2);
  __bf16* vtb = (__bf16*)carve((size_t)NB * C_DIM * HW_N * 2);
  __bf16* o1b = (__bf16*)carve((size_t)NB * HW_N * C_DIM * 2);
  float*  Sb  = (float*) carve((size_t)NB * HW_N * HW_N * 4);
  __bf16* Pb  = (__bf16*)carve((size_t)NB * HW_N * HW_N * 2);

  cvt_kernel<<<dim3(256), 256, 0, stream>>>(wq, wqb, C_DIM * C_DIM / 4);
  cvt_kernel<<<dim3(256), 256, 0, stream>>>(wk, wkb, C_DIM * C_DIM / 4);
  cvt_kernel<<<dim3(256), 256, 0, stream>>>(wv, wvb, C_DIM * C_DIM / 4);
  cvt_kernel<<<dim3(256), 256, 0, stream>>>(wo, wob, C_DIM * C_DIM / 4);

  const long long sNC = (long long)HW_N * C_DIM;  // 524288
  const long long sNN = (long long)HW_N * HW_N;   // 1048576

  for (int b0 = 0; b0 < Btot; b0 += NB) {
    const int nb = (Btot - b0 < NB) ? (Btot - b0) : NB;

    gn_kernel<<<dim3(nb * 8), 512, 0, stream>>>(x, gnw, gnb, hn, b0);

    // q = (hn^T x Wq^T + bq) * scale   -> bf16 [N=1024][O=512]
    gemm_bt<0, 1, true ><<<dim3(4, 8, nb), 256, 0, stream>>>(hn, wqb, qb, bq, nullptr,
        C_DIM, C_DIM, C_DIM, sNC, 0, sNC, SCALE_QK, C_DIM);
    // k
    gemm_bt<0, 1, false><<<dim3(4, 8, nb), 256, 0, stream>>>(hn, wkb, kb, bk, nullptr,
        C_DIM, C_DIM, C_DIM, sNC, 0, sNC, 1.f, C_DIM);
    // v^T = Wv x hn (out [C=512][N=1024], bias per row=channel)
    gemm_bt<0, 2, false><<<dim3(8, 4, nb), 256, 0, stream>>>(wvb, hn, vtb, bv, nullptr,
        C_DIM, C_DIM, HW_N, 0, sNC, sNC, 1.f, C_DIM);

    // S = q x k^T  (fp32 [1024][1024]); scale already folded into q
    gemm_bt<2, 0, false><<<dim3(8, 8, nb), 256, 0, stream>>>(qb, kb, Sb, nullptr, nullptr,
        C_DIM, C_DIM, HW_N, sNC, sNC, sNN, 1.f, C_DIM);

    softmax_kernel<<<dim3(nb * HW_N), 256, 0, stream>>>(Sb, Pb);

    // O1 = P x v^T^T  (out bf16 [N=1024][C=512])
    gemm_bt<0, 0, false><<<dim3(4, 8, nb), 256, 0, stream>>>(Pb, vtb, o1b, nullptr, nullptr,
        HW_N, HW_N, C_DIM, sNN, sNC, sNC, 1.f, HW_N);

    // out = Wo x O1^T + bo + x   (fp32 [C=512][N=1024], residual fused)
    gemm_bt<1, 2, false><<<dim3(8, 4, nb), 256, 0, stream>>>(wob, o1b,
        (float*)d_out + (long long)b0 * sNC, bo,
        x + (long long)b0 * sNC,
        C_DIM, C_DIM, HW_N, 0, sNC, sNC, 1.f, C_DIM);
  }
}

// Round 2
// 199.298 us; speedup vs baseline: 1.0548x; 1.0548x over previous
//
#include <hip/hip_runtime.h>
#include <stdint.h>

#define C_DIM 512
#define HW_N  1024
#define CPG   64
#define EPS_GN 1e-5f
#define SCALE_QK 0.044194173824159216f   // 512^-0.5
#define L2E 1.4426950408889634f

typedef __attribute__((ext_vector_type(8))) __bf16 bf16x8v;
typedef __attribute__((ext_vector_type(4))) float  f32x4;

typedef __attribute__((address_space(1))) void gvoid_t;
typedef __attribute__((address_space(3))) void lvoid_t;

__device__ __forceinline__ void gload_lds16(const void* g, void* l) {
  __builtin_amdgcn_global_load_lds((gvoid_t*)g, (lvoid_t*)l, 16, 0, 0);
}

__device__ __forceinline__ uint16_t f2bfbits(float f) {
  __bf16 h = (__bf16)f;
  return __builtin_bit_cast(uint16_t, h);
}

// ---------------------------------------------------------------------------
// GroupNorm -> hn^T bf16 [N][C]
// ---------------------------------------------------------------------------
__global__ __launch_bounds__(512)
void gn_kernel(const float* __restrict__ x, const float* __restrict__ gnw,
               const float* __restrict__ gnb, __bf16* __restrict__ hn)
{
  const int g  = blockIdx.x & 7;
  const int bl = blockIdx.x >> 3;
  const long long xbase = ((long long)bl * C_DIM + g * CPG) * HW_N;
  const int t = threadIdx.x;

  float s1 = 0.f, s2 = 0.f;
  const float4* xv = (const float4*)(x + xbase);
  for (int i = t; i < CPG * HW_N / 4; i += 512) {
    float4 v = xv[i];
    s1 += v.x + v.y + v.z + v.w;
    s2 += v.x * v.x + v.y * v.y + v.z * v.z + v.w * v.w;
  }
  #pragma unroll
  for (int off = 32; off; off >>= 1) {
    s1 += __shfl_xor(s1, off);
    s2 += __shfl_xor(s2, off);
  }
  __shared__ float red[2][8];
  const int w = t >> 6, l = t & 63;
  if (l == 0) { red[0][w] = s1; red[1][w] = s2; }
  __syncthreads();
  s1 = 0.f; s2 = 0.f;
  #pragma unroll
  for (int i = 0; i < 8; ++i) { s1 += red[0][i]; s2 += red[1][i]; }
  const float mean = s1 * (1.f / 65536.f);
  const float var  = s2 * (1.f / 65536.f) - mean * mean;
  const float rstd = rsqrtf(var + EPS_GN);

  __shared__ float tile[64][65];
  __bf16* outb = hn + (long long)bl * HW_N * C_DIM + g * CPG;
  for (int n0 = 0; n0 < HW_N; n0 += 64) {
    __syncthreads();
    #pragma unroll
    for (int rep = 0; rep < 8; ++rep) {
      const int cl = rep * 8 + (t >> 6);
      const int nl = t & 63;
      const float xval = x[xbase + (long long)cl * HW_N + n0 + nl];
      tile[cl][nl] = (xval - mean) * rstd * gnw[g * CPG + cl] + gnb[g * CPG + cl];
    }
    __syncthreads();
    #pragma unroll
    for (int rep = 0; rep < 8; ++rep) {
      const int nl = rep * 8 + (t >> 6);
      const int cl = t & 63;
      outb[(long long)(n0 + nl) * C_DIM + cl] = (__bf16)tile[cl][nl];
    }
  }
}

// ---------------------------------------------------------------------------
__global__ __launch_bounds__(256)
void cvt_kernel(const float* __restrict__ src, __bf16* __restrict__ dst,
                int n4, float scale)
{
  int i = blockIdx.x * 256 + threadIdx.x;
  if (i < n4) {
    float4 v = ((const float4*)src)[i];
    uint32_t lo = (uint32_t)f2bfbits(v.x * scale) | ((uint32_t)f2bfbits(v.y * scale) << 16);
    uint32_t hi = (uint32_t)f2bfbits(v.z * scale) | ((uint32_t)f2bfbits(v.w * scale) << 16);
    ((uint2*)dst)[i] = make_uint2(lo, hi);
  }
}

__global__ __launch_bounds__(256)
void bias_cat_kernel(const float* __restrict__ bq, const float* __restrict__ bk,
                     float* __restrict__ bqk)
{
  int i = blockIdx.x * 256 + threadIdx.x;
  if (i < 512)       bqk[i] = bq[i] * SCALE_QK;
  else if (i < 1024) bqk[i] = bk[i - 512];
}

// ---------------------------------------------------------------------------
// Generic bf16 GEMM, C[M][N] = A[M][K] x B[N][K]^T (m97-style).
// OUTM: 0=bf16, 1=f32+residual. BIASM: 0=none, 1=per-col, 2=per-row.
// ---------------------------------------------------------------------------
template<int OUTM, int BIASM>
__global__ __launch_bounds__(256)
void gemm_bt(const __bf16* __restrict__ Amat, const __bf16* __restrict__ Bmat,
             void* __restrict__ Cmat,
             const float* __restrict__ bias,
             const float* __restrict__ resid,
             int lda, int ldb, int ldc,
             long long aStride, long long bStride, long long cStride,
             int K)
{
  __shared__ alignas(16) __bf16 As[128 * 32];
  __shared__ alignas(16) __bf16 Bs[128 * 32];

  const int t  = threadIdx.x;
  const int w  = t >> 6;
  const int l  = t & 63;
  const int b  = blockIdx.z;
  const int n0 = blockIdx.x * 128;
  const int m0 = blockIdx.y * 128;

  const __bf16* Ab = Amat + (long long)b * aStride;
  const __bf16* Bb = Bmat + (long long)b * bStride;

  const int lr = l & 15;
  const int lg = l >> 4;
  const int wm = w >> 1;
  const int wn = w & 1;

  f32x4 acc[4][4];
  #pragma unroll
  for (int i = 0; i < 4; ++i)
    #pragma unroll
    for (int j = 0; j < 4; ++j)
      acc[i][j] = (f32x4){0.f, 0.f, 0.f, 0.f};

  const int flat0 = w * 1024 + l * 16;
  const int rowA  = flat0 >> 6;
  const int colA  = (flat0 & 63) >> 1;

  for (int k0 = 0; k0 < K; k0 += 32) {
    gload_lds16(Ab + (long long)(m0 + rowA     ) * lda + (k0 + colA), (char*)As + (w * 1024));
    gload_lds16(Ab + (long long)(m0 + rowA + 64) * lda + (k0 + colA), (char*)As + (4096 + w * 1024));
    gload_lds16(Bb + (long long)(n0 + rowA     ) * ldb + (k0 + colA), (char*)Bs + (w * 1024));
    gload_lds16(Bb + (long long)(n0 + rowA + 64) * ldb + (k0 + colA), (char*)Bs + (4096 + w * 1024));
    __syncthreads();

    bf16x8v af[4], bf[4];
    #pragma unroll
    for (int mi = 0; mi < 4; ++mi)
      af[mi] = *(const bf16x8v*)&As[(wm * 64 + mi * 16 + lr) * 32 + lg * 8];
    #pragma unroll
    for (int ni = 0; ni < 4; ++ni)
      bf[ni] = *(const bf16x8v*)&Bs[(wn * 64 + ni * 16 + lr) * 32 + lg * 8];

    #pragma unroll
    for (int mi = 0; mi < 4; ++mi)
      #pragma unroll
      for (int ni = 0; ni < 4; ++ni)
        acc[mi][ni] = __builtin_amdgcn_mfma_f32_16x16x32_bf16(af[mi], bf[ni], acc[mi][ni], 0, 0, 0);
    __syncthreads();
  }

  const int orow = m0 + wm * 64 + lg * 4;
  const int ocol = n0 + wn * 64 + lr;

  if (OUTM == 0) {
    __bf16* Cb = (__bf16*)Cmat + (long long)b * cStride;
    #pragma unroll
    for (int mi = 0; mi < 4; ++mi) {
      #pragma unroll
      for (int ni = 0; ni < 4; ++ni) {
        const int cc = ocol + ni * 16;
        const float cbias = (BIASM == 1) ? bias[cc] : 0.f;
        #pragma unroll
        for (int r = 0; r < 4; ++r) {
          const int rr = orow + mi * 16 + r;
          float v = acc[mi][ni][r];
          if (BIASM == 1) v += cbias;
          if (BIASM == 2) v += bias[rr];
          Cb[(long long)rr * ldc + cc] = (__bf16)v;
        }
      }
    }
  } else {
    float* Cf = (float*)Cmat + (long long)b * cStride;
    const float* Rf = resid + (long long)b * cStride;
    #pragma unroll
    for (int mi = 0; mi < 4; ++mi) {
      #pragma unroll
      for (int ni = 0; ni < 4; ++ni) {
        const int cc = ocol + ni * 16;
        const float cbias = (BIASM == 1) ? bias[cc] : 0.f;
        #pragma unroll
        for (int r = 0; r < 4; ++r) {
          const int rr = orow + mi * 16 + r;
          float v = acc[mi][ni][r];
          if (BIASM == 1) v += cbias;
          if (BIASM == 2) v += bias[rr];
          const long long idx = (long long)rr * ldc + cc;
          Cf[idx] = v + Rf[idx];
        }
      }
    }
  }
}

// ---------------------------------------------------------------------------
// Fused flash attention. qk: [B][1024][1024] bf16 (cols 0-511 = q*scale,
// 512-1023 = k). vt: [B][512][1024] bf16 (V^T, rows=c). o1: [B][1024][512].
// Block: 8 waves, QBLK=64 q-rows, iterate kv in steps of 64. Online softmax.
// ---------------------------------------------------------------------------
#define QBLK 64
#define KVBLK 64

__global__ __launch_bounds__(512, 2)
void flash_kernel(const __bf16* __restrict__ qk, const __bf16* __restrict__ vt,
                  __bf16* __restrict__ o1)
{
  // K rows are 512 bf16 = 1024B (64 granules of 16B), swizzle g ^= row&7
  // V rows are  64 bf16 =  128B ( 8 granules of 16B), swizzle g ^= row&7
  __shared__ alignas(16) __bf16 Ks[KVBLK * 512];
  __shared__ alignas(16) __bf16 Vs[512 * KVBLK];
  __shared__ alignas(16) __bf16 Ps[QBLK * KVBLK];
  __shared__ float mS[QBLK], lS[QBLK], facS[QBLK];
  __shared__ float red[QBLK][2];

  const int t  = threadIdx.x;
  const int w  = t >> 6;
  const int l  = t & 63;
  const int lr = l & 15;
  const int lg = l >> 4;

  // batch-major chunking so an XCD's blocks share K/V of ~2 batches
  const int lin = blockIdx.x;
  const int b    = (lin & 7) | ((lin >> 7) << 3);
  const int q0   = ((lin >> 3) & 15) * QBLK;

  const __bf16* qkb = qk + (long long)b * HW_N * 1024;
  const __bf16* vtb = vt + (long long)b * C_DIM * HW_N;

  const int sm  = w >> 1;   // QK^T role: S rows sm*16+:16
  const int sn2 = w & 1;    //            S cols sn2*32+:32
  const int wm  = w >> 2;   // PV role: O rows wm*32+:32
  const int wn  = w & 3;    //          O cols wn*128+:128

  // Q fragments in registers: row sm*16+lr, k = ks*32 + lg*8 (+:8)
  bf16x8v qreg[16];
  {
    const __bf16* qrow = qkb + (long long)(q0 + sm * 16 + lr) * 1024 + lg * 8;
    #pragma unroll
    for (int ks = 0; ks < 16; ++ks)
      qreg[ks] = *(const bf16x8v*)(qrow + ks * 32);
  }

  if (t < QBLK) { mS[t] = -1e30f; lS[t] = 0.f; }
  f32x4 acc[2][8];
  #pragma unroll
  for (int mi = 0; mi < 2; ++mi)
    #pragma unroll
    for (int nf = 0; nf < 8; ++nf)
      acc[mi][nf] = (f32x4){0.f, 0.f, 0.f, 0.f};

  for (int kv0 = 0; kv0 < HW_N; kv0 += KVBLK) {
    // ---- stage K tile [64][512] (swizzled source, linear LDS dest)
    #pragma unroll
    for (int i = 0; i < 8; ++i) {
      const int base = i * 8192 + w * 1024;
      const int f    = base + l * 16;
      const int row  = f >> 10;
      const int g    = (f >> 4) & 63;
      const int col  = ((g ^ (row & 7)) << 3);
      gload_lds16(qkb + (long long)(kv0 + row) * 1024 + 512 + col, (char*)Ks + base);
    }
    // ---- stage V tile [512][64]
    #pragma unroll
    for (int i = 0; i < 8; ++i) {
      const int base = i * 8192 + w * 1024;
      const int f    = base + l * 16;
      const int row  = f >> 7;
      const int g    = (f >> 4) & 7;
      const int col  = ((g ^ (row & 7)) << 3);
      gload_lds16(vtb + (long long)row * HW_N + kv0 + col, (char*)Vs + base);
    }
    __syncthreads();   // S1: tiles ready

    // ---- QK^T: two 16x16 fragments per wave
    f32x4 s0 = (f32x4){0.f, 0.f, 0.f, 0.f};
    f32x4 s1 = (f32x4){0.f, 0.f, 0.f, 0.f};
    const int r0 = (sn2 * 2 + 0) * 16 + lr;
    const int r1 = (sn2 * 2 + 1) * 16 + lr;
    #pragma unroll
    for (int ks = 0; ks < 16; ++ks) {
      const int g = ks * 4 + lg;
      bf16x8v b0 = *(const bf16x8v*)((char*)Ks + r0 * 1024 + ((g ^ (r0 & 7)) << 4));
      bf16x8v b1 = *(const bf16x8v*)((char*)Ks + r1 * 1024 + ((g ^ (r1 & 7)) << 4));
      s0 = __builtin_amdgcn_mfma_f32_16x16x32_bf16(qreg[ks], b0, s0, 0, 0, 0);
      s1 = __builtin_amdgcn_mfma_f32_16x16x32_bf16(qreg[ks], b1, s1, 0, 0, 0);
    }

    // ---- stats A: per-row tile max (reduce over 16 lanes = cols)
    float tm[4];
    #pragma unroll
    for (int r = 0; r < 4; ++r) {
      tm[r] = fmaxf(s0[r], s1[r]);
      #pragma unroll
      for (int off = 1; off < 16; off <<= 1)
        tm[r] = fmaxf(tm[r], __shfl_xor(tm[r], off));
    }
    if (lr == 0) {
      #pragma unroll
      for (int r = 0; r < 4; ++r) red[sm * 16 + lg * 4 + r][sn2] = tm[r];
    }
    __syncthreads();   // B1

    if (t < QBLK) {
      const float mo = mS[t];
      const float mn_ = fmaxf(mo, fmaxf(red[t][0], red[t][1]));
      mS[t] = mn_;
      facS[t] = exp2f((mo - mn_) * L2E);
    }
    __syncthreads();   // B2

    // ---- C: exp, write P (swizzled), row partial-sums, rescale own acc
    float rs[4];
    #pragma unroll
    for (int r = 0; r < 4; ++r) {
      const int row = sm * 16 + lg * 4 + r;
      const float mn_ = mS[row];
      const float p0 = exp2f((s0[r] - mn_) * L2E);
      const float p1 = exp2f((s1[r] - mn_) * L2E);
      rs[r] = p0 + p1;
      const int c0 = sn2 * 32 + lr;
      const int c1 = c0 + 16;
      const int g0 = c0 >> 3, g1 = c1 >> 3;
      *(__bf16*)((char*)Ps + row * 128 + ((g0 ^ (row & 7)) << 4) + ((c0 & 7) << 1)) = (__bf16)p0;
      *(__bf16*)((char*)Ps + row * 128 + ((g1 ^ (row & 7)) << 4) + ((c1 & 7) << 1)) = (__bf16)p1;
      #pragma unroll
      for (int off = 1; off < 16; off <<= 1) rs[r] += __shfl_xor(rs[r], off);
    }
    if (lr == 0) {
      #pragma unroll
      for (int r = 0; r < 4; ++r) red[sm * 16 + lg * 4 + r][sn2] = rs[r];
    }
    // rescale accumulator (PV-role rows)
    #pragma unroll
    for (int mi = 0; mi < 2; ++mi) {
      float fa[4];
      #pragma unroll
      for (int r = 0; r < 4; ++r) fa[r] = facS[wm * 32 + mi * 16 + lg * 4 + r];
      #pragma unroll
      for (int nf = 0; nf < 8; ++nf)
        #pragma unroll
        for (int r = 0; r < 4; ++r) acc[mi][nf][r] *= fa[r];
    }
    __syncthreads();   // C-end: Ps + sums ready

    if (t < QBLK) lS[t] = lS[t] * facS[t] + red[t][0] + red[t][1];

    // ---- PV: O[32x128 per wave] += P[32xKVBLK] x V[KVBLKx128]
    #pragma unroll
    for (int ks2 = 0; ks2 < 2; ++ks2) {
      bf16x8v pa[2];
      #pragma unroll
      for (int mi = 0; mi < 2; ++mi) {
        const int row = wm * 32 + mi * 16 + lr;
        const int g   = ks2 * 4 + lg;
        pa[mi] = *(const bf16x8v*)((char*)Ps + row * 128 + ((g ^ (row & 7)) << 4));
      }
      #pragma unroll
      for (int nf = 0; nf < 8; ++nf) {
        const int vr = wn * 128 + nf * 16 + lr;
        const int g  = ks2 * 4 + lg;
        bf16x8v vb = *(const bf16x8v*)((char*)Vs + vr * 128 + ((g ^ (vr & 7)) << 4));
        acc[0][nf] = __builtin_amdgcn_mfma_f32_16x16x32_bf16(pa[0], vb, acc[0][nf], 0, 0, 0);
        acc[1][nf] = __builtin_amdgcn_mfma_f32_16x16x32_bf16(pa[1], vb, acc[1][nf], 0, 0, 0);
      }
    }
    __syncthreads();   // end: tiles free for restage
  }

  // ---- epilogue: O = acc / l
  __bf16* ob = o1 + (long long)b * HW_N * C_DIM;
  #pragma unroll
  for (int mi = 0; mi < 2; ++mi) {
    float linv[4];
    #pragma unroll
    for (int r = 0; r < 4; ++r) linv[r] = 1.f / lS[wm * 32 + mi * 16 + lg * 4 + r];
    #pragma unroll
    for (int nf = 0; nf < 8; ++nf) {
      const int col = wn * 128 + nf * 16 + lr;
      #pragma unroll
      for (int r = 0; r < 4; ++r) {
        const int row = q0 + wm * 32 + mi * 16 + lg * 4 + r;
        ob[(long long)row * C_DIM + col] = (__bf16)(acc[mi][nf][r] * linv[r]);
      }
    }
  }
}

// ---------------------------------------------------------------------------
extern "C" void kernel_launch(void* const* d_in, const int* in_sizes, int n_in,
                              void* d_out, int out_size, void* d_ws, size_t ws_size,
                              hipStream_t stream)
{
  const float* x   = (const float*)d_in[0];
  const float* gnw = (const float*)d_in[1];
  const float* gnb = (const float*)d_in[2];
  const float* wq  = (const float*)d_in[3];
  const float* bq  = (const float*)d_in[4];
  const float* wk  = (const float*)d_in[5];
  const float* bk  = (const float*)d_in[6];
  const float* wv  = (const float*)d_in[7];
  const float* bv  = (const float*)d_in[8];
  const float* wo  = (const float*)d_in[9];
  const float* bo  = (const float*)d_in[10];
  (void)in_sizes; (void)n_in; (void)out_size; (void)ws_size;

  size_t used = 0;
  char* base = (char*)d_ws;
  auto carve = [&](size_t bytes) -> void* {
    used = (used + 255) & ~(size_t)255;
    void* p = base + used;
    used += bytes;
    return p;
  };

  __bf16* wqkb = (__bf16*)carve((size_t)2 * C_DIM * C_DIM * 2);  // [1024][512]
  __bf16* wvb  = (__bf16*)carve((size_t)C_DIM * C_DIM * 2);
  __bf16* wob  = (__bf16*)carve((size_t)C_DIM * C_DIM * 2);
  float*  bqk  = (float*) carve((size_t)1024 * 4);

  __bf16* hn   = (__bf16*)carve((size_t)16 * HW_N * C_DIM * 2);   // 16MB
  __bf16* qkb  = (__bf16*)carve((size_t)16 * HW_N * 1024 * 2);    // 32MB
  __bf16* vtb  = (__bf16*)carve((size_t)16 * C_DIM * HW_N * 2);   // 16MB
  __bf16* o1b  = (__bf16*)carve((size_t)16 * HW_N * C_DIM * 2);   // 16MB

  const long long sNC = (long long)HW_N * C_DIM;

  cvt_kernel<<<dim3(256), 256, 0, stream>>>(wq, wqkb, C_DIM * C_DIM / 4, SCALE_QK);
  cvt_kernel<<<dim3(256), 256, 0, stream>>>(wk, wqkb + (size_t)C_DIM * C_DIM, C_DIM * C_DIM / 4, 1.f);
  cvt_kernel<<<dim3(256), 256, 0, stream>>>(wv, wvb, C_DIM * C_DIM / 4, 1.f);
  cvt_kernel<<<dim3(256), 256, 0, stream>>>(wo, wob, C_DIM * C_DIM / 4, 1.f);
  bias_cat_kernel<<<dim3(4), 256, 0, stream>>>(bq, bk, bqk);

  gn_kernel<<<dim3(16 * 8), 512, 0, stream>>>(x, gnw, gnb, hn);

  // qk = hn x Wqk^T + bqk  -> bf16 [B][1024][1024]
  gemm_bt<0, 1><<<dim3(8, 8, 16), 256, 0, stream>>>(hn, wqkb, qkb, bqk, nullptr,
      C_DIM, C_DIM, 1024, sNC, 0, (long long)HW_N * 1024, C_DIM);
  // v^T = Wv x hn  -> bf16 [B][512][1024]
  gemm_bt<0, 2><<<dim3(8, 4, 16), 256, 0, stream>>>(wvb, hn, vtb, bv, nullptr,
      C_DIM, C_DIM, HW_N, 0, sNC, sNC, C_DIM);

  flash_kernel<<<dim3(256), 512, 0, stream>>>(qkb, vtb, o1b);

  // out = Wo x O1^T + bo + x  (fp32 [B][512][1024])
  gemm_bt<1, 2><<<dim3(8, 4, 16), 256, 0, stream>>>(wob, o1b, (float*)d_out, bo, x,
      C_DIM, C_DIM, HW_N, 0, sNC, sNC, C_DIM);
}

// Round 3
// 174.508 us; speedup vs baseline: 1.2046x; 1.1421x over previous
//
#include <hip/hip_runtime.h>
#include <stdint.h>

#define C_DIM 512
#define HW_N  1024
#define CPG   64
#define EPS_GN 1e-5f
#define SCALE_QK 0.044194173824159216f   // 512^-0.5

typedef __attribute__((ext_vector_type(8))) __bf16 bf16x8v;
typedef __attribute__((ext_vector_type(4))) float  f32x4;

typedef __attribute__((address_space(1))) void gvoid_t;
typedef __attribute__((address_space(3))) void lvoid_t;

__device__ __forceinline__ void gload_lds16(const void* g, void* l) {
  __builtin_amdgcn_global_load_lds((gvoid_t*)g, (lvoid_t*)l, 16, 0, 0);
}

__device__ __forceinline__ uint16_t f2bfbits(float f) {
  __bf16 h = (__bf16)f;
  return __builtin_bit_cast(uint16_t, h);
}

template<int N>
__device__ __forceinline__ void vm_wait() {
  if constexpr (N == 0) asm volatile("s_waitcnt vmcnt(0)" ::: "memory");
  else if constexpr (N == 3) asm volatile("s_waitcnt vmcnt(3)" ::: "memory");
  else asm volatile("s_waitcnt vmcnt(4)" ::: "memory");
}

// ---------------------------------------------------------------------------
// GroupNorm -> hn^T bf16 [N][C]
// ---------------------------------------------------------------------------
__global__ __launch_bounds__(512)
void gn_kernel(const float* __restrict__ x, const float* __restrict__ gnw,
               const float* __restrict__ gnb, __bf16* __restrict__ hn)
{
  const int g  = blockIdx.x & 7;
  const int bl = blockIdx.x >> 3;
  const long long xbase = ((long long)bl * C_DIM + g * CPG) * HW_N;
  const int t = threadIdx.x;

  float s1 = 0.f, s2 = 0.f;
  const float4* xv = (const float4*)(x + xbase);
  for (int i = t; i < CPG * HW_N / 4; i += 512) {
    float4 v = xv[i];
    s1 += v.x + v.y + v.z + v.w;
    s2 += v.x * v.x + v.y * v.y + v.z * v.z + v.w * v.w;
  }
  #pragma unroll
  for (int off = 32; off; off >>= 1) {
    s1 += __shfl_xor(s1, off);
    s2 += __shfl_xor(s2, off);
  }
  __shared__ float red[2][8];
  const int w = t >> 6, l = t & 63;
  if (l == 0) { red[0][w] = s1; red[1][w] = s2; }
  __syncthreads();
  s1 = 0.f; s2 = 0.f;
  #pragma unroll
  for (int i = 0; i < 8; ++i) { s1 += red[0][i]; s2 += red[1][i]; }
  const float mean = s1 * (1.f / 65536.f);
  const float var  = s2 * (1.f / 65536.f) - mean * mean;
  const float rstd = rsqrtf(var + EPS_GN);

  __shared__ float tile[64][65];
  __bf16* outb = hn + (long long)bl * HW_N * C_DIM + g * CPG;
  for (int n0 = 0; n0 < HW_N; n0 += 64) {
    __syncthreads();
    #pragma unroll
    for (int rep = 0; rep < 8; ++rep) {
      const int cl = rep * 8 + (t >> 6);
      const int nl = t & 63;
      const float xval = x[xbase + (long long)cl * HW_N + n0 + nl];
      tile[cl][nl] = (xval - mean) * rstd * gnw[g * CPG + cl] + gnb[g * CPG + cl];
    }
    __syncthreads();
    #pragma unroll
    for (int rep = 0; rep < 8; ++rep) {
      const int nl = rep * 8 + (t >> 6);
      const int cl = t & 63;
      outb[(long long)(n0 + nl) * C_DIM + cl] = (__bf16)tile[cl][nl];
    }
  }
}

// ---------------------------------------------------------------------------
__global__ __launch_bounds__(256)
void cvt_kernel(const float* __restrict__ src, __bf16* __restrict__ dst,
                int n4, float scale)
{
  int i = blockIdx.x * 256 + threadIdx.x;
  if (i < n4) {
    float4 v = ((const float4*)src)[i];
    uint32_t lo = (uint32_t)f2bfbits(v.x * scale) | ((uint32_t)f2bfbits(v.y * scale) << 16);
    uint32_t hi = (uint32_t)f2bfbits(v.z * scale) | ((uint32_t)f2bfbits(v.w * scale) << 16);
    ((uint2*)dst)[i] = make_uint2(lo, hi);
  }
}

__global__ __launch_bounds__(256)
void bias_cat_kernel(const float* __restrict__ bq, const float* __restrict__ bk,
                     float* __restrict__ bqk)
{
  int i = blockIdx.x * 256 + threadIdx.x;
  if (i < 512)       bqk[i] = bq[i] * SCALE_QK;
  else if (i < 1024) bqk[i] = bk[i - 512];
}

// ---------------------------------------------------------------------------
// Row softmax over S [rows][1024] fp32 -> P bf16 written IN-PLACE at the
// start of each fp32 row (P row stride = 2048 bf16 elems). Safe: all loads
// complete before the reduction barriers, writes land inside own row.
// ---------------------------------------------------------------------------
__global__ __launch_bounds__(256)
void softmax_kernel(float* __restrict__ S)
{
  const long long row = blockIdx.x;
  float* s = S + row * HW_N;
  const int t = threadIdx.x;
  float4 v = ((const float4*)s)[t];
  float m = fmaxf(fmaxf(v.x, v.y), fmaxf(v.z, v.w));
  #pragma unroll
  for (int off = 32; off; off >>= 1) m = fmaxf(m, __shfl_xor(m, off));
  __shared__ float redm[4];
  __shared__ float reds[4];
  const int w = t >> 6, l = t & 63;
  if (l == 0) redm[w] = m;
  __syncthreads();
  m = fmaxf(fmaxf(redm[0], redm[1]), fmaxf(redm[2], redm[3]));
  float e0 = __expf(v.x - m), e1 = __expf(v.y - m);
  float e2 = __expf(v.z - m), e3 = __expf(v.w - m);
  float sum = e0 + e1 + e2 + e3;
  #pragma unroll
  for (int off = 32; off; off >>= 1) sum += __shfl_xor(sum, off);
  if (l == 0) reds[w] = sum;
  __syncthreads();
  sum = reds[0] + reds[1] + reds[2] + reds[3];
  const float inv = 1.f / sum;
  uint32_t lo = (uint32_t)f2bfbits(e0 * inv) | ((uint32_t)f2bfbits(e1 * inv) << 16);
  uint32_t hi = (uint32_t)f2bfbits(e2 * inv) | ((uint32_t)f2bfbits(e3 * inv) << 16);
  ((uint2*)s)[t] = make_uint2(lo, hi);   // in-place bf16 P
}

// ---------------------------------------------------------------------------
// Pipelined bf16 GEMM: C[M][N] = A[M][K] x B[N][K]^T (both K-major).
// BM x 256 tile, BK=32, 8 waves (2 row x 4 col), ring-of-3 LDS buffers,
// counted vmcnt, 2 phases/K-step, XOR-swizzled LDS (granule ^= (row>>1)&3),
// swizzle applied via inverse-swizzled global source (linear LDS dest).
// OUTM: 0=bf16, 1=f32+bias+residual, 2=f32 plain. BIASM: 0 none, 1 per-col,
// 2 per-row.
// ---------------------------------------------------------------------------
template<int BM, int OUTM, int BIASM>
__global__ __launch_bounds__(512, 2)
void gemm8(const __bf16* __restrict__ Amat, const __bf16* __restrict__ Bmat,
           void* __restrict__ Cmat,
           const float* __restrict__ bias,
           const float* __restrict__ resid,
           int lda, int ldb, int ldc,
           long long aS, long long bS, long long cS, int K)
{
  constexpr int TILE_B = BM * 64 + 16384;   // bytes per ring slot (A + B)
  constexpr int CA = BM / 128;              // A chunks of 8KB
  constexpr int CH = CA + 2;                // total chunks per K-step
  constexpr int FPR = BM / 32;              // row frags per wave
  constexpr int FPP = FPR / 2;              // row frags per phase

  __shared__ alignas(16) char lds[3 * TILE_B];

  const int tt = threadIdx.x;
  const int w  = tt >> 6;
  const int l  = tt & 63;
  const int lr = l & 15;
  const int lg = l >> 4;
  const int wm = w >> 2;      // 0..1 row wave
  const int wn = w & 3;       // 0..3 col wave
  const int b  = blockIdx.z;
  const int n0 = blockIdx.x * 256;
  const int m0 = blockIdx.y * BM;

  const __bf16* Ab = Amat + (long long)b * aS;
  const __bf16* Bb = Bmat + (long long)b * bS;

  // staging geometry (per thread): 16B at chunk byte tt*16
  const int srow = tt >> 2;                       // row within 128-row chunk
  const int sgr  = (tt & 3) ^ ((tt >> 3) & 3);    // inverse-swizzled granule

  f32x4 acc[FPR][4];
  #pragma unroll
  for (int f = 0; f < FPR; ++f)
    #pragma unroll
    for (int c = 0; c < 4; ++c)
      acc[f][c] = (f32x4){0.f, 0.f, 0.f, 0.f};

  auto stage = [&](int t, int c) {
    const int k0 = t << 5;
    char* dst = lds + (t % 3) * TILE_B + c * 8192 + w * 1024;  // wave-uniform
    const __bf16* src;
    if (c < CA) src = Ab + (long long)(m0 + c * 128 + srow) * lda + k0 + sgr * 8;
    else        src = Bb + (long long)(n0 + (c - CA) * 128 + srow) * ldb + k0 + sgr * 8;
    gload_lds16(src, dst);
  };
  auto rdA = [&](const char* base, int f) -> bf16x8v {
    const int row = wm * (BM / 2) + f * 16 + lr;
    return *(const bf16x8v*)(base + row * 64 + ((lg ^ ((row >> 1) & 3)) << 4));
  };
  auto rdB = [&](const char* base, int c) -> bf16x8v {
    const int row = wn * 64 + c * 16 + lr;
    return *(const bf16x8v*)(base + BM * 64 + row * 64 + ((lg ^ ((row >> 1) & 3)) << 4));
  };

  const int NT = K >> 5;

  #pragma unroll
  for (int c = 0; c < CH; ++c) stage(0, c);
  #pragma unroll
  for (int c = 0; c < CH; ++c) stage(1, c);

  for (int t = 0; t < NT; ++t) {
    const char* buf = lds + (t % 3) * TILE_B;
    if (t + 1 < NT) vm_wait<CH>();
    else            vm_wait<0>();
    __builtin_amdgcn_s_barrier();
    __builtin_amdgcn_sched_barrier(0);

    // ---- phase 0: B frags + first row-half
    bf16x8v Bf[4];
    #pragma unroll
    for (int c = 0; c < 4; ++c) Bf[c] = rdB(buf, c);
    bf16x8v Af[FPP];
    #pragma unroll
    for (int f = 0; f < FPP; ++f) Af[f] = rdA(buf, f);
    if (t + 2 < NT) { stage(t + 2, 0); stage(t + 2, 1); }
    asm volatile("s_waitcnt lgkmcnt(0)" ::: "memory");
    __builtin_amdgcn_sched_barrier(0);
    __builtin_amdgcn_s_setprio(1);
    #pragma unroll
    for (int f = 0; f < FPP; ++f)
      #pragma unroll
      for (int c = 0; c < 4; ++c)
        acc[f][c] = __builtin_amdgcn_mfma_f32_16x16x32_bf16(Af[f], Bf[c], acc[f][c], 0, 0, 0);
    __builtin_amdgcn_s_setprio(0);
    __builtin_amdgcn_s_barrier();
    __builtin_amdgcn_sched_barrier(0);

    // ---- phase 1: second row-half
    bf16x8v Ag[FPP];
    #pragma unroll
    for (int f = 0; f < FPP; ++f) Ag[f] = rdA(buf, FPP + f);
    if (t + 2 < NT) {
      #pragma unroll
      for (int c = 2; c < CH; ++c) stage(t + 2, c);
    }
    asm volatile("s_waitcnt lgkmcnt(0)" ::: "memory");
    __builtin_amdgcn_sched_barrier(0);
    __builtin_amdgcn_s_setprio(1);
    #pragma unroll
    for (int f = 0; f < FPP; ++f)
      #pragma unroll
      for (int c = 0; c < 4; ++c)
        acc[FPP + f][c] = __builtin_amdgcn_mfma_f32_16x16x32_bf16(Ag[f], Bf[c], acc[FPP + f][c], 0, 0, 0);
    __builtin_amdgcn_s_setprio(0);
    __builtin_amdgcn_s_barrier();
    __builtin_amdgcn_sched_barrier(0);
  }

  // ---- epilogue: C/D layout col=lane&15, row=(lane>>4)*4+reg
  #pragma unroll
  for (int f = 0; f < FPR; ++f) {
    const int rrb = m0 + wm * (BM / 2) + f * 16 + lg * 4;
    #pragma unroll
    for (int c = 0; c < 4; ++c) {
      const int cc = n0 + wn * 64 + c * 16 + lr;
      const float cbias = (BIASM == 1) ? bias[cc] : 0.f;
      #pragma unroll
      for (int r = 0; r < 4; ++r) {
        const int rr = rrb + r;
        float v = acc[f][c][r];
        if (BIASM == 1) v += cbias;
        if (BIASM == 2) v += bias[rr];
        const long long idx = (long long)rr * ldc + cc;
        if (OUTM == 0) {
          ((__bf16*)Cmat + (long long)b * cS)[idx] = (__bf16)v;
        } else if (OUTM == 2) {
          ((float*)Cmat + (long long)b * cS)[idx] = v;
        } else {
          float* Cf = (float*)Cmat + (long long)b * cS;
          const float* Rf = resid + (long long)b * cS;
          Cf[idx] = v + Rf[idx];
        }
      }
    }
  }
}

// ---------------------------------------------------------------------------
extern "C" void kernel_launch(void* const* d_in, const int* in_sizes, int n_in,
                              void* d_out, int out_size, void* d_ws, size_t ws_size,
                              hipStream_t stream)
{
  const float* x   = (const float*)d_in[0];
  const float* gnw = (const float*)d_in[1];
  const float* gnb = (const float*)d_in[2];
  const float* wq  = (const float*)d_in[3];
  const float* bq  = (const float*)d_in[4];
  const float* wk  = (const float*)d_in[5];
  const float* bk  = (const float*)d_in[6];
  const float* wv  = (const float*)d_in[7];
  const float* bv  = (const float*)d_in[8];
  const float* wo  = (const float*)d_in[9];
  const float* bo  = (const float*)d_in[10];
  (void)in_sizes; (void)n_in; (void)out_size; (void)ws_size;

  size_t used = 0;
  char* base = (char*)d_ws;
  auto carve = [&](size_t bytes) -> void* {
    used = (used + 255) & ~(size_t)255;
    void* p = base + used;
    used += bytes;
    return p;
  };

  __bf16* wqkb = (__bf16*)carve((size_t)2 * C_DIM * C_DIM * 2);  // [1024][512]
  __bf16* wvb  = (__bf16*)carve((size_t)C_DIM * C_DIM * 2);
  __bf16* wob  = (__bf16*)carve((size_t)C_DIM * C_DIM * 2);
  float*  bqk  = (float*) carve((size_t)1024 * 4);

  __bf16* hn   = (__bf16*)carve((size_t)16 * HW_N * C_DIM * 2);   // 16MB
  __bf16* qkb  = (__bf16*)carve((size_t)16 * HW_N * 1024 * 2);    // 32MB
  __bf16* vtb  = (__bf16*)carve((size_t)16 * C_DIM * HW_N * 2);   // 16MB
  __bf16* o1b  = (__bf16*)carve((size_t)16 * HW_N * C_DIM * 2);   // 16MB
  float*  Sb   = (float*) carve((size_t)16 * HW_N * HW_N * 4);    // 64MB (P in-place)

  const long long sNC = (long long)HW_N * C_DIM;   // 524288
  const long long sNN = (long long)HW_N * 1024;    // 1048576

  cvt_kernel<<<dim3(256), 256, 0, stream>>>(wq, wqkb, C_DIM * C_DIM / 4, SCALE_QK);
  cvt_kernel<<<dim3(256), 256, 0, stream>>>(wk, wqkb + (size_t)C_DIM * C_DIM, C_DIM * C_DIM / 4, 1.f);
  cvt_kernel<<<dim3(256), 256, 0, stream>>>(wv, wvb, C_DIM * C_DIM / 4, 1.f);
  cvt_kernel<<<dim3(256), 256, 0, stream>>>(wo, wob, C_DIM * C_DIM / 4, 1.f);
  bias_cat_kernel<<<dim3(4), 256, 0, stream>>>(bq, bk, bqk);

  gn_kernel<<<dim3(16 * 8), 512, 0, stream>>>(x, gnw, gnb, hn);

  // qk = hn x Wqk^T + bqk  -> bf16 [B][1024][1024] (cols 0-511 q*scale, 512+ k)
  gemm8<256, 0, 1><<<dim3(4, 4, 16), 512, 0, stream>>>(hn, wqkb, qkb, bqk, nullptr,
      C_DIM, C_DIM, 1024, sNC, 0, sNN, C_DIM);

  // v^T = Wv x hn + bv(row)  -> bf16 [B][512][1024]
  gemm8<128, 0, 2><<<dim3(4, 4, 16), 512, 0, stream>>>(wvb, hn, vtb, bv, nullptr,
      C_DIM, C_DIM, HW_N, 0, sNC, sNC, C_DIM);

  // S = q x k^T  -> fp32 [B][1024][1024]
  gemm8<256, 2, 0><<<dim3(4, 4, 16), 512, 0, stream>>>(qkb, qkb + 512, Sb, nullptr, nullptr,
      1024, 1024, 1024, sNN, sNN, sNN, C_DIM);

  // softmax rows, P bf16 in-place (row stride 2048 bf16)
  softmax_kernel<<<dim3(16 * 1024), 256, 0, stream>>>(Sb);

  // O1 = P x V  -> bf16 [B][1024][512]
  gemm8<128, 0, 0><<<dim3(2, 8, 16), 512, 0, stream>>>((const __bf16*)Sb, vtb, o1b,
      nullptr, nullptr,
      2048, 1024, C_DIM, (long long)HW_N * 2048, sNC, sNC, HW_N);

  // out = Wo x O1^T + bo + x  (fp32 [B][512][1024], residual fused)
  gemm8<128, 1, 2><<<dim3(4, 4, 16), 512, 0, stream>>>(wob, o1b, (float*)d_out, bo, x,
      C_DIM, C_DIM, HW_N, 0, sNC, sNC, C_DIM);
}

// Round 4
// 158.306 us; speedup vs baseline: 1.3279x; 1.1023x over previous
//
#include <hip/hip_runtime.h>
#include <stdint.h>

#define C_DIM 512
#define HW_N  1024
#define CPG   64
#define EPS_GN 1e-5f
#define SCALE_QK 0.044194173824159216f   // 512^-0.5

typedef __attribute__((ext_vector_type(8))) __bf16 bf16x8v;
typedef __attribute__((ext_vector_type(4))) float  f32x4;

typedef __attribute__((address_space(1))) void gvoid_t;
typedef __attribute__((address_space(3))) void lvoid_t;

__device__ __forceinline__ void gload_lds16(const void* g, void* l) {
  __builtin_amdgcn_global_load_lds((gvoid_t*)g, (lvoid_t*)l, 16, 0, 0);
}

__device__ __forceinline__ uint16_t f2bfbits(float f) {
  __bf16 h = (__bf16)f;
  return __builtin_bit_cast(uint16_t, h);
}

__device__ __forceinline__ float bf2f(uint16_t u) {
  return __builtin_bit_cast(float, (uint32_t)u << 16);
}

template<int N>
__device__ __forceinline__ void vm_wait() {
  if constexpr (N == 0) asm volatile("s_waitcnt vmcnt(0)" ::: "memory");
  else if constexpr (N == 3) asm volatile("s_waitcnt vmcnt(3)" ::: "memory");
  else asm volatile("s_waitcnt vmcnt(4)" ::: "memory");
}

// ---------------------------------------------------------------------------
// GN stats: 256 blocks = (b, g, half). Each sums 64c x 512n with float4.
// Deterministic fp32 partials -> part[(b*8+g)*2+half] = {s1, s2}.
// ---------------------------------------------------------------------------
__global__ __launch_bounds__(256)
void gn_stats(const float* __restrict__ x, float2* __restrict__ part)
{
  const int lin  = blockIdx.x;
  const int b    = lin >> 4;
  const int g    = (lin >> 1) & 7;
  const int half = lin & 1;
  const int t    = threadIdx.x;

  const float4* xv = (const float4*)(x + ((long long)(b * C_DIM + g * CPG)) * HW_N
                                       + half * 512);
  float s1 = 0.f, s2 = 0.f;
  for (int i = t; i < 64 * 128; i += 256) {
    const int c  = i >> 7;
    const int nf = i & 127;
    float4 v = xv[c * 256 + nf];
    s1 += v.x + v.y + v.z + v.w;
    s2 += v.x * v.x + v.y * v.y + v.z * v.z + v.w * v.w;
  }
  #pragma unroll
  for (int off = 32; off; off >>= 1) {
    s1 += __shfl_xor(s1, off);
    s2 += __shfl_xor(s2, off);
  }
  __shared__ float red[2][4];
  const int w = t >> 6, l = t & 63;
  if (l == 0) { red[0][w] = s1; red[1][w] = s2; }
  __syncthreads();
  if (t == 0) {
    s1 = red[0][0] + red[0][1] + red[0][2] + red[0][3];
    s2 = red[1][0] + red[1][1] + red[1][2] + red[1][3];
    part[lin] = make_float2(s1, s2);
  }
}

// ---------------------------------------------------------------------------
// GN normalize + transpose: 256 blocks = (b, nchunk of 64 n), 512 threads.
// Per-channel a/b coefficients in LDS; 64c x 64n fp32 tile transpose;
// bf16x8 (16B) stores into hn^T [N][C].
// ---------------------------------------------------------------------------
__global__ __launch_bounds__(512)
void gn_norm(const float* __restrict__ x, const float2* __restrict__ part,
             const float* __restrict__ gnw, const float* __restrict__ gnb,
             __bf16* __restrict__ hn)
{
  const int b  = blockIdx.x >> 4;
  const int nc = blockIdx.x & 15;
  const int t  = threadIdx.x;

  __shared__ float asc[512], bsc[512];
  __shared__ float tile[64][65];

  {
    const int c = t;
    const int g = c >> 6;
    float2 p0 = part[(b * 8 + g) * 2 + 0];
    float2 p1 = part[(b * 8 + g) * 2 + 1];
    const float mean = (p0.x + p1.x) * (1.f / 65536.f);
    const float var  = (p0.y + p1.y) * (1.f / 65536.f) - mean * mean;
    const float rstd = rsqrtf(var + EPS_GN);
    const float a = rstd * gnw[c];
    asc[c] = a;
    bsc[c] = gnb[c] - mean * a;
  }
  __syncthreads();

  const long long xb = (long long)b * C_DIM * HW_N + nc * 64;
  __bf16* ob = hn + ((long long)b * HW_N + nc * 64) * C_DIM;

  for (int cg = 0; cg < 8; ++cg) {
    #pragma unroll
    for (int pass = 0; pass < 2; ++pass) {
      const int task = pass * 512 + t;
      const int c  = task >> 4;
      const int f4 = task & 15;
      float4 v = *(const float4*)(x + xb + (long long)(cg * 64 + c) * HW_N + f4 * 4);
      const float a  = asc[cg * 64 + c];
      const float bb = bsc[cg * 64 + c];
      tile[c][f4 * 4 + 0] = v.x * a + bb;
      tile[c][f4 * 4 + 1] = v.y * a + bb;
      tile[c][f4 * 4 + 2] = v.z * a + bb;
      tile[c][f4 * 4 + 3] = v.w * a + bb;
    }
    __syncthreads();
    {
      const int n  = t >> 3;
      const int gc = t & 7;
      uint32_t p[4];
      #pragma unroll
      for (int j = 0; j < 4; ++j) {
        const float f0 = tile[gc * 8 + 2 * j + 0][n];
        const float f1 = tile[gc * 8 + 2 * j + 1][n];
        p[j] = (uint32_t)f2bfbits(f0) | ((uint32_t)f2bfbits(f1) << 16);
      }
      *(uint4*)(ob + (long long)n * C_DIM + cg * 64 + gc * 8) =
          make_uint4(p[0], p[1], p[2], p[3]);
    }
    __syncthreads();
  }
}

// ---------------------------------------------------------------------------
// One prep kernel: 4 weight conversions (+scale fold on Wq) + bias concat.
// ---------------------------------------------------------------------------
__global__ __launch_bounds__(256)
void prep_kernel(const float* __restrict__ wq, const float* __restrict__ wk,
                 const float* __restrict__ wv, const float* __restrict__ wo,
                 const float* __restrict__ bq, const float* __restrict__ bk,
                 __bf16* __restrict__ wqkb, __bf16* __restrict__ wvb,
                 __bf16* __restrict__ wob, float* __restrict__ bqk)
{
  const int blk = blockIdx.x;
  if (blk < 1024) {
    const int which = blk >> 8;
    const int i = (blk & 255) * 256 + threadIdx.x;   // float4 index < 65536
    const float* src = (which == 0) ? wq : (which == 1) ? wk : (which == 2) ? wv : wo;
    __bf16* dst = (which == 0) ? wqkb
               : (which == 1) ? (wqkb + (size_t)C_DIM * C_DIM)
               : (which == 2) ? wvb : wob;
    const float scale = (which == 0) ? SCALE_QK : 1.f;
    float4 v = ((const float4*)src)[i];
    uint32_t lo = (uint32_t)f2bfbits(v.x * scale) | ((uint32_t)f2bfbits(v.y * scale) << 16);
    uint32_t hi = (uint32_t)f2bfbits(v.z * scale) | ((uint32_t)f2bfbits(v.w * scale) << 16);
    ((uint2*)dst)[i] = make_uint2(lo, hi);
  } else {
    for (int j = threadIdx.x; j < 1024; j += 256)
      bqk[j] = (j < 512) ? bq[j] * SCALE_QK : bk[j - 512];
  }
}

// ---------------------------------------------------------------------------
// Row softmax over bf16 S [rows][1024], in-place -> bf16 P. 256 thr/row.
// ---------------------------------------------------------------------------
__global__ __launch_bounds__(256)
void softmax_kernel(__bf16* __restrict__ S)
{
  const long long row = blockIdx.x;
  uint2* sp = (uint2*)(S + row * HW_N);
  const int t = threadIdx.x;
  uint2 raw = sp[t];
  float v0 = bf2f((uint16_t)(raw.x & 0xffff));
  float v1 = bf2f((uint16_t)(raw.x >> 16));
  float v2 = bf2f((uint16_t)(raw.y & 0xffff));
  float v3 = bf2f((uint16_t)(raw.y >> 16));
  float m = fmaxf(fmaxf(v0, v1), fmaxf(v2, v3));
  #pragma unroll
  for (int off = 32; off; off >>= 1) m = fmaxf(m, __shfl_xor(m, off));
  __shared__ float redm[4];
  __shared__ float reds[4];
  const int w = t >> 6, l = t & 63;
  if (l == 0) redm[w] = m;
  __syncthreads();
  m = fmaxf(fmaxf(redm[0], redm[1]), fmaxf(redm[2], redm[3]));
  float e0 = __expf(v0 - m), e1 = __expf(v1 - m);
  float e2 = __expf(v2 - m), e3 = __expf(v3 - m);
  float sum = e0 + e1 + e2 + e3;
  #pragma unroll
  for (int off = 32; off; off >>= 1) sum += __shfl_xor(sum, off);
  if (l == 0) reds[w] = sum;
  __syncthreads();
  sum = reds[0] + reds[1] + reds[2] + reds[3];
  const float inv = 1.f / sum;
  uint32_t lo = (uint32_t)f2bfbits(e0 * inv) | ((uint32_t)f2bfbits(e1 * inv) << 16);
  uint32_t hi = (uint32_t)f2bfbits(e2 * inv) | ((uint32_t)f2bfbits(e3 * inv) << 16);
  sp[t] = make_uint2(lo, hi);
}

// ---------------------------------------------------------------------------
// Pipelined bf16 GEMM: C[M][N] = A[M][K] x B[N][K]^T (both K-major).
// BM x 256 tile, BK=32, 8 waves (2x4), ring-of-3 LDS, counted vmcnt,
// 2 phases/K-step, XOR-swizzled LDS via inverse-swizzled global source.
// OUTM: 0=bf16, 1=f32+bias+residual, 2=f32. BIASM: 0 none, 1 col, 2 row.
// ---------------------------------------------------------------------------
template<int BM, int OUTM, int BIASM>
__global__ __launch_bounds__(512, 2)
void gemm8(const __bf16* __restrict__ Amat, const __bf16* __restrict__ Bmat,
           void* __restrict__ Cmat,
           const float* __restrict__ bias,
           const float* __restrict__ resid,
           int lda, int ldb, int ldc,
           long long aS, long long bS, long long cS, int K)
{
  constexpr int TILE_B = BM * 64 + 16384;
  constexpr int CA = BM / 128;
  constexpr int CH = CA + 2;
  constexpr int FPR = BM / 32;
  constexpr int FPP = FPR / 2;

  __shared__ alignas(16) char lds[3 * TILE_B];

  const int tt = threadIdx.x;
  const int w  = tt >> 6;
  const int l  = tt & 63;
  const int lr = l & 15;
  const int lg = l >> 4;
  const int wm = w >> 2;
  const int wn = w & 3;
  const int b  = blockIdx.z;
  const int n0 = blockIdx.x * 256;
  const int m0 = blockIdx.y * BM;

  const __bf16* Ab = Amat + (long long)b * aS;
  const __bf16* Bb = Bmat + (long long)b * bS;

  const int srow = tt >> 2;
  const int sgr  = (tt & 3) ^ ((tt >> 3) & 3);

  f32x4 acc[FPR][4];
  #pragma unroll
  for (int f = 0; f < FPR; ++f)
    #pragma unroll
    for (int c = 0; c < 4; ++c)
      acc[f][c] = (f32x4){0.f, 0.f, 0.f, 0.f};

  auto stage = [&](int t, int c) {
    const int k0 = t << 5;
    char* dst = lds + (t % 3) * TILE_B + c * 8192 + w * 1024;
    const __bf16* src;
    if (c < CA) src = Ab + (long long)(m0 + c * 128 + srow) * lda + k0 + sgr * 8;
    else        src = Bb + (long long)(n0 + (c - CA) * 128 + srow) * ldb + k0 + sgr * 8;
    gload_lds16(src, dst);
  };
  auto rdA = [&](const char* base, int f) -> bf16x8v {
    const int row = wm * (BM / 2) + f * 16 + lr;
    return *(const bf16x8v*)(base + row * 64 + ((lg ^ ((row >> 1) & 3)) << 4));
  };
  auto rdB = [&](const char* base, int c) -> bf16x8v {
    const int row = wn * 64 + c * 16 + lr;
    return *(const bf16x8v*)(base + BM * 64 + row * 64 + ((lg ^ ((row >> 1) & 3)) << 4));
  };

  const int NT = K >> 5;

  #pragma unroll
  for (int c = 0; c < CH; ++c) stage(0, c);
  #pragma unroll
  for (int c = 0; c < CH; ++c) stage(1, c);

  for (int t = 0; t < NT; ++t) {
    const char* buf = lds + (t % 3) * TILE_B;
    if (t + 1 < NT) vm_wait<CH>();
    else            vm_wait<0>();
    __builtin_amdgcn_s_barrier();
    __builtin_amdgcn_sched_barrier(0);

    bf16x8v Bf[4];
    #pragma unroll
    for (int c = 0; c < 4; ++c) Bf[c] = rdB(buf, c);
    bf16x8v Af[FPP];
    #pragma unroll
    for (int f = 0; f < FPP; ++f) Af[f] = rdA(buf, f);
    if (t + 2 < NT) { stage(t + 2, 0); stage(t + 2, 1); }
    asm volatile("s_waitcnt lgkmcnt(0)" ::: "memory");
    __builtin_amdgcn_sched_barrier(0);
    __builtin_amdgcn_s_setprio(1);
    #pragma unroll
    for (int f = 0; f < FPP; ++f)
      #pragma unroll
      for (int c = 0; c < 4; ++c)
        acc[f][c] = __builtin_amdgcn_mfma_f32_16x16x32_bf16(Af[f], Bf[c], acc[f][c], 0, 0, 0);
    __builtin_amdgcn_s_setprio(0);
    __builtin_amdgcn_s_barrier();
    __builtin_amdgcn_sched_barrier(0);

    bf16x8v Ag[FPP];
    #pragma unroll
    for (int f = 0; f < FPP; ++f) Ag[f] = rdA(buf, FPP + f);
    if (t + 2 < NT) {
      #pragma unroll
      for (int c = 2; c < CH; ++c) stage(t + 2, c);
    }
    asm volatile("s_waitcnt lgkmcnt(0)" ::: "memory");
    __builtin_amdgcn_sched_barrier(0);
    __builtin_amdgcn_s_setprio(1);
    #pragma unroll
    for (int f = 0; f < FPP; ++f)
      #pragma unroll
      for (int c = 0; c < 4; ++c)
        acc[FPP + f][c] = __builtin_amdgcn_mfma_f32_16x16x32_bf16(Ag[f], Bf[c], acc[FPP + f][c], 0, 0, 0);
    __builtin_amdgcn_s_setprio(0);
    __builtin_amdgcn_s_barrier();
    __builtin_amdgcn_sched_barrier(0);
  }

  #pragma unroll
  for (int f = 0; f < FPR; ++f) {
    const int rrb = m0 + wm * (BM / 2) + f * 16 + lg * 4;
    #pragma unroll
    for (int c = 0; c < 4; ++c) {
      const int cc = n0 + wn * 64 + c * 16 + lr;
      const float cbias = (BIASM == 1) ? bias[cc] : 0.f;
      #pragma unroll
      for (int r = 0; r < 4; ++r) {
        const int rr = rrb + r;
        float v = acc[f][c][r];
        if (BIASM == 1) v += cbias;
        if (BIASM == 2) v += bias[rr];
        const long long idx = (long long)rr * ldc + cc;
        if (OUTM == 0) {
          ((__bf16*)Cmat + (long long)b * cS)[idx] = (__bf16)v;
        } else if (OUTM == 2) {
          ((float*)Cmat + (long long)b * cS)[idx] = v;
        } else {
          float* Cf = (float*)Cmat + (long long)b * cS;
          const float* Rf = resid + (long long)b * cS;
          Cf[idx] = v + Rf[idx];
        }
      }
    }
  }
}

// ---------------------------------------------------------------------------
extern "C" void kernel_launch(void* const* d_in, const int* in_sizes, int n_in,
                              void* d_out, int out_size, void* d_ws, size_t ws_size,
                              hipStream_t stream)
{
  const float* x   = (const float*)d_in[0];
  const float* gnw = (const float*)d_in[1];
  const float* gnb = (const float*)d_in[2];
  const float* wq  = (const float*)d_in[3];
  const float* bq  = (const float*)d_in[4];
  const float* wk  = (const float*)d_in[5];
  const float* bk  = (const float*)d_in[6];
  const float* wv  = (const float*)d_in[7];
  const float* bv  = (const float*)d_in[8];
  const float* wo  = (const float*)d_in[9];
  const float* bo  = (const float*)d_in[10];
  (void)in_sizes; (void)n_in; (void)out_size; (void)ws_size;

  size_t used = 0;
  char* base = (char*)d_ws;
  auto carve = [&](size_t bytes) -> void* {
    used = (used + 255) & ~(size_t)255;
    void* p = base + used;
    used += bytes;
    return p;
  };

  __bf16* wqkb = (__bf16*)carve((size_t)2 * C_DIM * C_DIM * 2);
  __bf16* wvb  = (__bf16*)carve((size_t)C_DIM * C_DIM * 2);
  __bf16* wob  = (__bf16*)carve((size_t)C_DIM * C_DIM * 2);
  float*  bqk  = (float*) carve((size_t)1024 * 4);
  float2* part = (float2*)carve((size_t)256 * 8);

  __bf16* hn   = (__bf16*)carve((size_t)16 * HW_N * C_DIM * 2);   // 16MB
  __bf16* qkb  = (__bf16*)carve((size_t)16 * HW_N * 1024 * 2);    // 32MB
  __bf16* vtb  = (__bf16*)carve((size_t)16 * C_DIM * HW_N * 2);   // 16MB
  __bf16* o1b  = (__bf16*)carve((size_t)16 * HW_N * C_DIM * 2);   // 16MB
  __bf16* Sb   = (__bf16*)carve((size_t)16 * HW_N * HW_N * 2);    // 32MB

  const long long sNC = (long long)HW_N * C_DIM;   // 524288
  const long long sNN = (long long)HW_N * 1024;    // 1048576

  prep_kernel<<<dim3(1025), 256, 0, stream>>>(wq, wk, wv, wo, bq, bk,
                                              wqkb, wvb, wob, bqk);
  gn_stats<<<dim3(256), 256, 0, stream>>>(x, part);
  gn_norm<<<dim3(256), 512, 0, stream>>>(x, part, gnw, gnb, hn);

  // qk = hn x Wqk^T + bqk  -> bf16 [B][1024][1024] (cols 0-511 q*scale, 512+ k)
  gemm8<256, 0, 1><<<dim3(4, 4, 16), 512, 0, stream>>>(hn, wqkb, qkb, bqk, nullptr,
      C_DIM, C_DIM, 1024, sNC, 0, sNN, C_DIM);

  // v^T = Wv x hn + bv(row)  -> bf16 [B][512][1024]
  gemm8<128, 0, 2><<<dim3(4, 4, 16), 512, 0, stream>>>(wvb, hn, vtb, bv, nullptr,
      C_DIM, C_DIM, HW_N, 0, sNC, sNC, C_DIM);

  // S = q x k^T  -> bf16 [B][1024][1024]
  gemm8<256, 0, 0><<<dim3(4, 4, 16), 512, 0, stream>>>(qkb, qkb + 512, Sb, nullptr, nullptr,
      1024, 1024, 1024, sNN, sNN, sNN, C_DIM);

  // softmax rows, P bf16 in-place
  softmax_kernel<<<dim3(16 * 1024), 256, 0, stream>>>(Sb);

  // O1 = P x V  -> bf16 [B][1024][512]
  gemm8<128, 0, 0><<<dim3(2, 8, 16), 512, 0, stream>>>(Sb, vtb, o1b,
      nullptr, nullptr, 1024, 1024, C_DIM, sNN, sNC, sNC, HW_N);

  // out = Wo x O1^T + bo + x  (fp32 [B][512][1024], residual fused)
  gemm8<128, 1, 2><<<dim3(4, 4, 16), 512, 0, stream>>>(wob, o1b, (float*)d_out, bo, x,
      C_DIM, C_DIM, HW_N, 0, sNC, sNC, C_DIM);
}